// Round 9
// baseline (355.988 us; speedup 1.0000x reference)
//
#include <hip/hip_runtime.h>
#include <cstddef>

typedef unsigned short u16;
typedef __attribute__((ext_vector_type(8))) short bf8;   // 8 x bf16 (4 VGPRs)
typedef __attribute__((ext_vector_type(4))) float f4;
typedef __attribute__((ext_vector_type(4))) unsigned short us4;

#define NATOMS 11776
#define NBLK   368

__device__ __forceinline__ u16 f2b(float x){
  union { float f; unsigned u; } v; v.f = x;
  unsigned r = v.u + 0x7fffu + ((v.u >> 16) & 1u);
  return (u16)(r >> 16);
}
__device__ __forceinline__ float b2f(u16 x){
  union { unsigned u; float f; } v; v.u = ((unsigned)x) << 16;
  return v.f;
}
__device__ __forceinline__ f4 f4zero(){ f4 z = {0.f,0.f,0.f,0.f}; return z; }
__device__ __forceinline__ f4 mfma16(bf8 a, bf8 b, f4 c){
  return __builtin_amdgcn_mfma_f32_16x16x32_bf16(a, b, c, 0, 0, 0);
}
__device__ __forceinline__ int iclamp(int v, int lo, int hi){ return v < lo ? lo : (v > hi ? hi : v); }
__device__ __forceinline__ void lds_fence(){
  asm volatile("s_waitcnt lgkmcnt(0)" ::: "memory");
  __builtin_amdgcn_sched_barrier(0);
}
__device__ __forceinline__ bf8 cvt_f32x8(const float* __restrict__ p){
  float4 a = *(const float4*)p, b = *(const float4*)(p + 4);
  bf8 o;
  o[0] = (short)f2b(a.x); o[1] = (short)f2b(a.y); o[2] = (short)f2b(a.z); o[3] = (short)f2b(a.w);
  o[4] = (short)f2b(b.x); o[5] = (short)f2b(b.y); o[6] = (short)f2b(b.z); o[7] = (short)f2b(b.w);
  return o;
}

// ---------------------------------------------------------------- convert fp32 -> bf16 (weights only)
struct CvtArgs {
  const float* src[11];
  u16* dst[11];
  int n4[11];
};

__global__ __launch_bounds__(256) void k_convert(CvtArgs a){
  int stride = gridDim.x * 256;
  int tid = blockIdx.x * 256 + threadIdx.x;
  for (int s = 0; s < 11; ++s){
    const float4* src = (const float4*)a.src[s];
    us4* dst = (us4*)a.dst[s];
    int n = a.n4[s];
    for (int i = tid; i < n; i += stride){
      float4 v = src[i];
      us4 o;
      o.x = f2b(v.x); o.y = f2b(v.y); o.z = f2b(v.z); o.w = f2b(v.w);
      dst[i] = o;
    }
  }
}

// ---------------------------------------------------------------- generic 16-row MFMA strip GEMM
template<int N, int K, int LDA = K>
__device__ __forceinline__ void gemm_strip(const u16* __restrict__ A, const u16* __restrict__ W, float* L){
  constexpr int CPW = N / 4;
  constexpr int T = CPW / 16;
  const int lane = threadIdx.x & 63;
  const int wave = threadIdx.x >> 6;
  const int rr = lane & 15, grp = lane >> 4;
  f4 acc[T];
#pragma unroll
  for (int t = 0; t < T; ++t) acc[t] = f4zero();
#pragma unroll
  for (int kc = 0; kc < K / 32; ++kc){
    bf8 af = *(const bf8*)(A + rr * LDA + kc * 32 + grp * 8);
#pragma unroll
    for (int t = 0; t < T; ++t){
      const u16* wp = W + (size_t)(wave * CPW + t * 16 + rr) * K + kc * 32 + grp * 8;
      acc[t] = mfma16(af, *(const bf8*)wp, acc[t]);
    }
  }
#pragma unroll
  for (int t = 0; t < T; ++t)
#pragma unroll
    for (int r = 0; r < 4; ++r)
      L[(grp * 4 + r) * N + wave * CPW + t * 16 + rr] = acc[t][r];
}

// paired adaLN gemm: N=256 output, wave owns gb1 cols [w*32,+32) and gb2 cols [128+w*32,+32);
// x = sigmoid(gb1)*LNf + gb2 written directly to X (bf16, LDA 136). A has stride LDA_A.
template<int LDA_A>
__device__ __forceinline__ void gemm_adaln(const u16* __restrict__ A, const u16* __restrict__ W,
                                           const float* __restrict__ LNf, u16* __restrict__ X){
  const int lane = threadIdx.x & 63;
  const int wave = threadIdx.x >> 6;
  const int rr = lane & 15, grp = lane >> 4;
  f4 acc[4];
#pragma unroll
  for (int t = 0; t < 4; ++t) acc[t] = f4zero();
#pragma unroll
  for (int kc = 0; kc < 4; ++kc){
    bf8 af = *(const bf8*)(A + rr * LDA_A + kc * 32 + grp * 8);
#pragma unroll
    for (int t = 0; t < 4; ++t){
      int col0 = (t < 2) ? wave * 32 + t * 16 : 128 + wave * 32 + (t - 2) * 16;
      acc[t] = mfma16(af, *(const bf8*)(W + (size_t)(col0 + rr) * 128 + kc * 32 + grp * 8), acc[t]);
    }
  }
#pragma unroll
  for (int t = 0; t < 2; ++t)
#pragma unroll
    for (int r = 0; r < 4; ++r){
      int row = grp * 4 + r, c = wave * 32 + t * 16 + rr;
      float s = 1.f / (1.f + __expf(-acc[t][r]));
      X[row * 136 + c] = f2b(s * LNf[row * 128 + c] + acc[t + 2][r]);
    }
}

// ---------------------------------------------------------------- fused: cond + LN + ph/pw + pre(layer 0)
__global__ __launch_bounds__(256) void k_cond_pre(const float* __restrict__ af, const float* __restrict__ Wc,
                                                  const float* __restrict__ Wph, const float* __restrict__ Wpw,
                                                  float* __restrict__ a_f, u16* __restrict__ sln_bf,
                                                  float* __restrict__ ph, float* __restrict__ pw,
                                                  const u16* __restrict__ slnW, const u16* __restrict__ qkvW,
                                                  const float* __restrict__ qb, u16* __restrict__ qkv_out){
  __shared__ float LB[16 * 384];
  __shared__ __align__(16) u16 Xs[16 * 136];  // s_ln bf16
  __shared__ __align__(16) u16 Xr[16 * 136];  // relu(s_ln) bf16
  __shared__ __align__(16) u16 Xx[16 * 136];  // x bf16
  __shared__ float LNf[16 * 128];             // s_ln f32
  const int strip = blockIdx.x;
  const int lane = threadIdx.x & 63, wave = threadIdx.x >> 6;
  const int rr = lane & 15, grp = lane >> 4;
  // 1. c = af @ Wc^T
  {
    f4 acc[2];
    acc[0] = f4zero(); acc[1] = f4zero();
#pragma unroll
    for (int kc = 0; kc < 4; ++kc){
      bf8 afr = cvt_f32x8(af + (size_t)(strip * 16 + rr) * 128 + kc * 32 + grp * 8);
#pragma unroll
      for (int t = 0; t < 2; ++t){
        bf8 bfr = cvt_f32x8(Wc + (size_t)(wave * 32 + t * 16 + rr) * 128 + kc * 32 + grp * 8);
        acc[t] = mfma16(afr, bfr, acc[t]);
      }
    }
#pragma unroll
    for (int t = 0; t < 2; ++t)
#pragma unroll
      for (int r = 0; r < 4; ++r)
        LB[(grp * 4 + r) * 128 + wave * 32 + t * 16 + rr] = acc[t][r];
  }
  __syncthreads();
  // 2. LN -> a_f, sln_bf, Xs, Xr, LNf
  {
    int r = threadIdx.x >> 4, s = threadIdx.x & 15;
    float sum = 0.f, sq = 0.f;
#pragma unroll
    for (int j = 0; j < 8; ++j){ float v = LB[r * 128 + s * 8 + j]; sum += v; sq += v * v; }
#pragma unroll
    for (int m = 1; m < 16; m <<= 1){ sum += __shfl_xor(sum, m); sq += __shfl_xor(sq, m); }
    float mu = sum * (1.f / 128.f);
    float var = sq * (1.f / 128.f) - mu * mu;
    float rs = rsqrtf(var + 1e-5f);
#pragma unroll
    for (int j = 0; j < 8; ++j){
      int c = s * 8 + j;
      float v = LB[r * 128 + c];
      size_t idx = (size_t)(strip * 16 + r) * 128 + c;
      a_f[idx] = v;
      float ln = (v - mu) * rs;
      LNf[r * 128 + c] = ln;
      u16 lb = f2b(ln);
      sln_bf[idx] = lb;
      Xs[r * 136 + c] = lb;
      Xr[r * 136 + c] = f2b(fmaxf(ln, 0.f));
    }
  }
  __syncthreads();
  // 3. paired sln-gemm + adaLN -> Xx (registers, no LB round-trip)
  gemm_adaln<136>(Xs, slnW, LNf, Xx);
  __syncthreads();
  // 4. qkv = x @ qkvW
  gemm_strip<384, 128, 136>(Xx, qkvW, LB);
  __syncthreads();
  const float scale = 0.17677669529663687f;
  for (int i = threadIdx.x; i < 16 * 384; i += 256){
    int r = i / 384, c = i - r * 384;
    float v = LB[i];
    if (c < 128) v = (v + qb[c]) * scale;
    qkv_out[(size_t)(strip * 16 + r) * 384 + c] = f2b(v);
  }
  // 5. ph/pw (waves 0/1, reads Xr)
  if (wave < 2){
    const float* Wsel = wave ? Wpw : Wph;
    f4 acc = f4zero();
#pragma unroll
    for (int kc = 0; kc < 4; ++kc){
      bf8 afr = *(const bf8*)(&Xr[rr * 136 + kc * 32 + grp * 8]);
      bf8 bfr = cvt_f32x8(Wsel + (size_t)rr * 128 + kc * 32 + grp * 8);
      acc = mfma16(afr, bfr, acc);
    }
    float* out = wave ? pw : ph;
#pragma unroll
    for (int r = 0; r < 4; ++r)
      out[(size_t)(strip * 16 + grp * 4 + r) * 16 + rr] = acc[r];
  }
}

// ---------------------------------------------------------------- fused post(l) [+ pre(l+1) | + tok relu-GEMM]
template<int LAST>
__global__ __launch_bounds__(256) void k_postpre(const u16* __restrict__ sln, const float* __restrict__ lnA,
                                                 float* __restrict__ a,
                                                 const u16* __restrict__ gateW, const float* __restrict__ gbias,
                                                 const u16* __restrict__ adaW, const u16* __restrict__ taW,
                                                 const u16* __restrict__ tbW,
                                                 const u16* __restrict__ slnW2, const u16* __restrict__ qkvW2,
                                                 const float* __restrict__ qb2, u16* __restrict__ qkv_out,
                                                 const u16* __restrict__ tokW, float* __restrict__ atom_out){
  __shared__ float LB[16 * 384];
  __shared__ __align__(16) u16 X[16 * 136];
  __shared__ __align__(16) u16 G[16 * 264];
  __shared__ float LNf[16 * 128];
  const int strip = blockIdx.x;
  const int lane = threadIdx.x & 63, wave = threadIdx.x >> 6;
  const int rr = lane & 15, grp = lane >> 4;
  const u16* Ag = sln + (size_t)strip * 2048;
  // 1. fused gate|ada gemm (N=384, per-tile weight select), one A pass
  {
    f4 acc[6];
#pragma unroll
    for (int t = 0; t < 6; ++t) acc[t] = f4zero();
#pragma unroll
    for (int kc = 0; kc < 4; ++kc){
      bf8 af = *(const bf8*)(Ag + rr * 128 + kc * 32 + grp * 8);
#pragma unroll
      for (int t = 0; t < 6; ++t){
        int row0 = wave * 96 + t * 16;
        const u16* W = (row0 < 128) ? gateW + (size_t)(row0 + rr) * 128
                                    : adaW + (size_t)(row0 - 128 + rr) * 128;
        acc[t] = mfma16(af, *(const bf8*)(W + kc * 32 + grp * 8), acc[t]);
      }
    }
#pragma unroll
    for (int t = 0; t < 6; ++t)
#pragma unroll
      for (int r = 0; r < 4; ++r)
        LB[(grp * 4 + r) * 384 + wave * 96 + t * 16 + rr] = acc[t][r];
  }
  __syncthreads();
  // 2. gate -> registers; x -> X
  float gv[8];
#pragma unroll
  for (int ii = 0; ii < 8; ++ii){
    int i = threadIdx.x + 256 * ii;
    int r = i >> 7, c = i & 127;
    gv[ii] = 1.f / (1.f + __expf(-(LB[r * 384 + c] + gbias[c])));
  }
  for (int i = threadIdx.x; i < 2048; i += 256){
    int r = i >> 7, c = i & 127;
    float g1 = LB[r * 384 + 128 + c], g2 = LB[r * 384 + 256 + c];
    float s = 1.f / (1.f + __expf(-g1));
    X[r * 136 + c] = f2b(s * lnA[(size_t)(strip * 16 + r) * 128 + c] + g2);
  }
  __syncthreads();
  // 3. ta gemm with paired tiles -> register GLU -> G (no LB round-trip)
  {
    f4 acc[8];
#pragma unroll
    for (int t = 0; t < 8; ++t) acc[t] = f4zero();
#pragma unroll
    for (int kc = 0; kc < 4; ++kc){
      bf8 af = *(const bf8*)(&X[rr * 136 + kc * 32 + grp * 8]);
#pragma unroll
      for (int t = 0; t < 8; ++t){
        int col0 = (t < 4) ? wave * 64 + t * 16 : 256 + wave * 64 + (t - 4) * 16;
        acc[t] = mfma16(af, *(const bf8*)(taW + (size_t)(col0 + rr) * 128 + kc * 32 + grp * 8), acc[t]);
      }
    }
#pragma unroll
    for (int t = 0; t < 4; ++t)
#pragma unroll
      for (int r = 0; r < 4; ++r){
        float ab1 = acc[t][r], ab2 = acc[t + 4][r];
        G[(grp * 4 + r) * 264 + wave * 64 + t * 16 + rr] = f2b(ab1 / (1.f + __expf(-ab1)) * ab2);
      }
  }
  __syncthreads();
  // 4. h = g @ tbW
  gemm_strip<128, 256, 264>(G, tbW, LB);
  __syncthreads();
  // 5. gated residual
#pragma unroll
  for (int ii = 0; ii < 8; ++ii){
    int i = threadIdx.x + 256 * ii;
    size_t idx = (size_t)strip * 2048 + i;
    float v = a[idx] + gv[ii] * LB[i];
    a[idx] = v;
    LB[i] = v;
    if (LAST){ int r = i >> 7, c = i & 127; X[r * 136 + c] = f2b(v); }
  }
  __syncthreads();
  if (!LAST){
    // 6. LN (LDS only)
    {
      int r = threadIdx.x >> 4, s = threadIdx.x & 15;
      float sum = 0.f, sq = 0.f;
#pragma unroll
      for (int j = 0; j < 8; ++j){ float v = LB[r * 128 + s * 8 + j]; sum += v; sq += v * v; }
#pragma unroll
      for (int m = 1; m < 16; m <<= 1){ sum += __shfl_xor(sum, m); sq += __shfl_xor(sq, m); }
      float mu = sum * (1.f / 128.f);
      float var = sq * (1.f / 128.f) - mu * mu;
      float rs = rsqrtf(var + 1e-5f);
#pragma unroll
      for (int j = 0; j < 8; ++j){
        int c = s * 8 + j;
        LNf[r * 128 + c] = (LB[r * 128 + c] - mu) * rs;
      }
    }
    __syncthreads();
    // 7. paired sln2-gemm + adaLN -> X
    gemm_adaln<128>(Ag, slnW2, LNf, X);
    __syncthreads();
    // 8. qkv2
    gemm_strip<384, 128, 136>(X, qkvW2, LB);
    __syncthreads();
    const float scale = 0.17677669529663687f;
    for (int i = threadIdx.x; i < 16 * 384; i += 256){
      int r = i / 384, c = i - r * 384;
      float v = LB[i];
      if (c < 128) v = (v + qb2[c]) * scale;
      qkv_out[(size_t)(strip * 16 + r) * 384 + c] = f2b(v);
    }
  } else {
    gemm_strip<384, 128, 136>(X, tokW, LB);
    __syncthreads();
    const size_t base = (size_t)strip * 16 * 384;
    for (int i = threadIdx.x; i < 16 * 384; i += 256) atom_out[base + i] = fmaxf(LB[i], 0.f);
  }
}

// ---------------------------------------------------------------- pair-bias MLP: all-MFMA, zero shuffles
__global__ __launch_bounds__(256) void k_pb(const float* __restrict__ ph, const float* __restrict__ pw,
                                            const float* __restrict__ W1, const float* __restrict__ W2,
                                            const float* __restrict__ lnw, const float* __restrict__ lnb,
                                            const float* __restrict__ pbw, float* __restrict__ bias){
  __shared__ __align__(16) u16 mt[4][16 * 24];
  __shared__ __align__(16) u16 vt[4][16 * 24];
  const int t = threadIdx.x;
  const int lane = t & 63, wave = t >> 6;
  const int rr = lane & 15, grp = lane >> 4;
  const int b = blockIdx.x >> 3, qg = blockIdx.x & 7;
  const int q = qg * 4 + wave;
  const int qa = b * 32 + q;

  bf8 wf1 = {0,0,0,0,0,0,0,0}, wf2 = {0,0,0,0,0,0,0,0};
  bf8 bproj = {0,0,0,0,0,0,0,0}, bones = {0,0,0,0,0,0,0,0};
  if (grp < 2){
#pragma unroll
    for (int j = 0; j < 8; ++j){
      wf1[j] = (short)f2b(W1[rr * 16 + grp * 8 + j]);
      wf2[j] = (short)f2b(W2[rr * 16 + grp * 8 + j]);
      bones[j] = (short)0x3F80;
    }
    if (rr < 4){
#pragma unroll
      for (int j = 0; j < 8; ++j)
        bproj[j] = (short)f2b(pbw[rr * 16 + grp * 8 + j] * lnw[grp * 8 + j]);
    }
  }
  float w2s_r = 0.f, bb_r = 0.f;
  if (rr < 4){
#pragma unroll
    for (int cc = 0; cc < 16; ++cc){
      float pv = pbw[rr * 16 + cc];
      w2s_r += pv * lnw[cc];
      bb_r  += pv * lnb[cc];
    }
  }
  const float* phq = ph + (size_t)qa * 16;
  float pha[8];
  if (grp < 2){
#pragma unroll
    for (int j = 0; j < 8; ++j) pha[j] = phq[grp * 8 + j];
  }
  const float ph_r = phq[rr];
  u16* mw = &mt[wave][0];
  u16* vw = &vt[wave][0];

  for (int kt = 0; kt < 8; ++kt){
    const int k0 = kt * 16;
    bf8 af = {0,0,0,0,0,0,0,0};
    if (grp < 2){
      int winA = b * 32 + k0 + rr - 48;
      int kaA = iclamp(winA, 0, NATOMS - 1);
      const float* pwr = pw + (size_t)kaA * 16 + grp * 8;
#pragma unroll
      for (int j = 0; j < 8; ++j) af[j] = (short)f2b(fmaxf(pha[j] + pwr[j], 0.f));
    }
    f4 c1 = mfma16(af, wf1, f4zero());
#pragma unroll
    for (int r = 0; r < 4; ++r)
      mw[(grp * 4 + r) * 24 + rr] = f2b(fmaxf(c1[r], 0.f));
    lds_fence();
    bf8 mf = {0,0,0,0,0,0,0,0};
    if (grp < 2) mf = *(const bf8*)(mw + rr * 24 + grp * 8);
    f4 c2 = mfma16(mf, wf2, f4zero());
#pragma unroll
    for (int r = 0; r < 4; ++r){
      int win = b * 32 + k0 + grp * 4 + r - 48;
      int ka = iclamp(win, 0, NATOMS - 1);
      float v = c2[r] + ph_r + pw[(size_t)ka * 16 + rr];
      vw[(grp * 4 + r) * 24 + rr] = f2b(v);
    }
    lds_fence();
    bf8 vf = {0,0,0,0,0,0,0,0}, vf2 = {0,0,0,0,0,0,0,0};
    if (grp < 2){
      vf = *(const bf8*)(vw + rr * 24 + grp * 8);
#pragma unroll
      for (int j = 0; j < 8; ++j){
        float x = b2f((u16)vf[j]);
        union { float f; unsigned u; } s; s.f = x * x;
        vf2[j] = (short)(u16)(s.u >> 16);
      }
    }
    f4 T1 = mfma16(vf, bproj, f4zero());
    f4 T2 = mfma16(vf, bones, f4zero());
    f4 T3 = mfma16(vf2, bones, f4zero());
    if (rr < 4){
      float4 o;
      float ov[4];
#pragma unroll
      for (int r = 0; r < 4; ++r){
        int win = b * 32 + k0 + grp * 4 + r - 48;
        bool valid = (win >= 0) && (win < NATOMS);
        float S = T2[r], Q = T3[r], d = T1[r];
        float mu = S * (1.f / 16.f);
        float var = Q * (1.f / 16.f) - mu * mu;
        float rq = rsqrtf(var + 1e-5f);
        ov[r] = rq * (d - mu * w2s_r) + bb_r + (valid ? 0.f : -1e9f);
      }
      o.x = ov[0]; o.y = ov[1]; o.z = ov[2]; o.w = ov[3];
      *(float4*)(bias + ((size_t)((b * 4 + rr) * 32) + q) * 128 + k0 + grp * 4) = o;
    }
  }
}

// ---------------------------------------------------------------- block attention + out-proj + residual + row-LN
__global__ __launch_bounds__(256) void k_attn(const u16* __restrict__ qkv, const float* __restrict__ bias,
                                              const u16* __restrict__ outw, const float* __restrict__ outb,
                                              float* __restrict__ a, float* __restrict__ lnA){
  __shared__ u16 VT[128][136];
  __shared__ u16 P[4][32 * 136];
  __shared__ u16 O[32][136];
  __shared__ float part2[32][8];
  const int t = threadIdx.x;
  const int lane = t & 63, wave = t >> 6;
  const int b = blockIdx.x;
  const int rr = lane & 15, grp = lane >> 4;

  for (int i = 0; i < 8; ++i){
    int s = t + 256 * i;
    int ka = s & 127, d0 = (s >> 7) * 8;
    int win = b * 32 + ka - 48;
    int src = iclamp(win, 0, NATOMS - 1);
    bf8 v = *(const bf8*)(qkv + (size_t)src * 384 + 256 + d0);
#pragma unroll
    for (int j = 0; j < 8; ++j) VT[d0 + j][ka] = (u16)v[j];
  }
  __syncthreads();

  const int h = wave;
  bf8 kfr[8];
#pragma unroll
  for (int kt = 0; kt < 8; ++kt){
    int ka = kt * 16 + rr;
    int win = b * 32 + ka - 48;
    int src = iclamp(win, 0, NATOMS - 1);
    kfr[kt] = *(const bf8*)(qkv + (size_t)src * 384 + 128 + h * 32 + grp * 8);
  }
  f4 S[2][8];
#pragma unroll
  for (int qt = 0; qt < 2; ++qt){
    bf8 qf = *(const bf8*)(qkv + (size_t)(b * 32 + qt * 16 + rr) * 384 + h * 32 + grp * 8);
#pragma unroll
    for (int kt = 0; kt < 8; ++kt){
      S[qt][kt] = f4zero();
      S[qt][kt] = mfma16(qf, kfr[kt], S[qt][kt]);
    }
  }
  const float* brow = bias + (size_t)((b * 4 + h) * 32) * 128;
#pragma unroll
  for (int qt = 0; qt < 2; ++qt){
#pragma unroll
    for (int r = 0; r < 4; ++r){
      int q = qt * 16 + grp * 4 + r;
      float vals[8];
      float mx = -1e30f;
#pragma unroll
      for (int kt = 0; kt < 8; ++kt){
        float v = S[qt][kt][r] + brow[q * 128 + kt * 16 + rr];
        vals[kt] = v;
        mx = fmaxf(mx, v);
      }
#pragma unroll
      for (int m = 1; m < 16; m <<= 1) mx = fmaxf(mx, __shfl_xor(mx, m));
      float sum = 0.f;
#pragma unroll
      for (int kt = 0; kt < 8; ++kt){ vals[kt] = __expf(vals[kt] - mx); sum += vals[kt]; }
#pragma unroll
      for (int m = 1; m < 16; m <<= 1) sum += __shfl_xor(sum, m);
      float inv = 1.f / sum;
#pragma unroll
      for (int kt = 0; kt < 8; ++kt)
        P[h][q * 136 + kt * 16 + rr] = f2b(vals[kt] * inv);
    }
  }
  __syncthreads();
  f4 oacc[2][2];
#pragma unroll
  for (int qt = 0; qt < 2; ++qt)
#pragma unroll
    for (int dt = 0; dt < 2; ++dt) oacc[qt][dt] = f4zero();
#pragma unroll
  for (int kc = 0; kc < 4; ++kc){
#pragma unroll
    for (int qt = 0; qt < 2; ++qt){
      bf8 pa = *(const bf8*)(&P[h][(qt * 16 + rr) * 136 + kc * 32 + grp * 8]);
#pragma unroll
      for (int dt = 0; dt < 2; ++dt){
        bf8 vb = *(const bf8*)(&VT[h * 32 + dt * 16 + rr][kc * 32 + grp * 8]);
        oacc[qt][dt] = mfma16(pa, vb, oacc[qt][dt]);
      }
    }
  }
#pragma unroll
  for (int qt = 0; qt < 2; ++qt)
#pragma unroll
    for (int dt = 0; dt < 2; ++dt)
#pragma unroll
      for (int r = 0; r < 4; ++r)
        O[qt * 16 + grp * 4 + r][h * 32 + dt * 16 + rr] = f2b(oacc[qt][dt][r]);
  __syncthreads();
  f4 pacc[2][2];
#pragma unroll
  for (int qt = 0; qt < 2; ++qt)
#pragma unroll
    for (int ct = 0; ct < 2; ++ct) pacc[qt][ct] = f4zero();
#pragma unroll
  for (int kc = 0; kc < 4; ++kc){
    bf8 a0 = *(const bf8*)(&O[rr][kc * 32 + grp * 8]);
    bf8 a1 = *(const bf8*)(&O[16 + rr][kc * 32 + grp * 8]);
#pragma unroll
    for (int ct = 0; ct < 2; ++ct){
      bf8 wf = *(const bf8*)(outw + (size_t)(wave * 32 + ct * 16 + rr) * 128 + kc * 32 + grp * 8);
      pacc[0][ct] = mfma16(a0, wf, pacc[0][ct]);
      pacc[1][ct] = mfma16(a1, wf, pacc[1][ct]);
    }
  }
  float vv[2][2][4];
#pragma unroll
  for (int qt = 0; qt < 2; ++qt)
#pragma unroll
    for (int ct = 0; ct < 2; ++ct)
#pragma unroll
      for (int r = 0; r < 4; ++r){
        int q = qt * 16 + grp * 4 + r;
        int col = wave * 32 + ct * 16 + rr;
        size_t idx = (size_t)(b * 32 + q) * 128 + col;
        float v = a[idx] + pacc[qt][ct][r] + outb[col];
        a[idx] = v;
        vv[qt][ct][r] = v;
      }
#pragma unroll
  for (int qt = 0; qt < 2; ++qt)
#pragma unroll
    for (int r = 0; r < 4; ++r){
      float ps = vv[qt][0][r] + vv[qt][1][r];
      float pq = vv[qt][0][r] * vv[qt][0][r] + vv[qt][1][r] * vv[qt][1][r];
#pragma unroll
      for (int m = 1; m < 16; m <<= 1){ ps += __shfl_xor(ps, m); pq += __shfl_xor(pq, m); }
      if (rr == 0){
        int q = qt * 16 + grp * 4 + r;
        part2[q][wave * 2] = ps;
        part2[q][wave * 2 + 1] = pq;
      }
    }
  __syncthreads();
#pragma unroll
  for (int qt = 0; qt < 2; ++qt)
#pragma unroll
    for (int r = 0; r < 4; ++r){
      int q = qt * 16 + grp * 4 + r;
      f4 p0 = *(const f4*)&part2[q][0];
      f4 p1 = *(const f4*)&part2[q][4];
      float S = p0[0] + p0[2] + p1[0] + p1[2];
      float Q = p0[1] + p0[3] + p1[1] + p1[3];
      float mu = S * (1.f / 128.f);
      float var = Q * (1.f / 128.f) - mu * mu;
      float rs = rsqrtf(var + 1e-5f);
#pragma unroll
      for (int ct = 0; ct < 2; ++ct){
        int col = wave * 32 + ct * 16 + rr;
        lnA[(size_t)(b * 32 + q) * 128 + col] = (vv[qt][ct][r] - mu) * rs;
      }
    }
}

// ---------------------------------------------------------------- segment mean (atoms -> tokens)
__device__ __forceinline__ int lbound(const int* __restrict__ arr, int n, int v){
  int lo = 0, hi = n;
  while (lo < hi){ int mid = (lo + hi) >> 1; if (arr[mid] < v) lo = mid + 1; else hi = mid; }
  return lo;
}

__global__ __launch_bounds__(256) void k_segmean(const float* __restrict__ atom_out,
                                                 const int* __restrict__ a2t, u16* __restrict__ tokbf){
  const int tok = blockIdx.x;
  __shared__ int lo_s, hi_s;
  if (threadIdx.x == 0){
    lo_s = lbound(a2t, NATOMS, tok);
    hi_s = lbound(a2t, NATOMS, tok + 1);
  }
  __syncthreads();
  int lo = lo_s, hi = hi_s;
  float inv = 1.f / fmaxf((float)(hi - lo), 1.f);
  for (int c = threadIdx.x; c < 384; c += 256){
    float s = 0.f;
    for (int aa = lo; aa < hi; ++aa) s += atom_out[(size_t)aa * 384 + c];
    tokbf[(size_t)tok * 384 + c] = f2b(s * inv);
  }
}

// ---------------------------------------------------------------- token head: grid 128 (strip x col-quarter)
__global__ __launch_bounds__(256) void k_tok(const u16* __restrict__ tok, const u16* __restrict__ catW,
                                             float* __restrict__ s_trunk, float* __restrict__ s_struct,
                                             float* __restrict__ u_f){
  __shared__ float LB[16 * 256];
  const int strip = blockIdx.x >> 2, quad = blockIdx.x & 3;
  gemm_strip<256, 384>(tok + (size_t)strip * 16 * 384, catW + (size_t)quad * 256 * 384, LB);
  __syncthreads();
  for (int i = threadIdx.x; i < 16 * 256; i += 256){
    int r = i >> 8, c = i & 255;
    int row = strip * 16 + r;
    int cg = quad * 256 + c;
    float v = LB[i];
    if (cg < 384) s_trunk[(size_t)row * 384 + cg] = v;
    else if (cg < 768) s_struct[(size_t)row * 384 + (cg - 384)] = v;
    else u_f[(size_t)row * 256 + (cg - 768)] = v;
  }
}

// ---------------------------------------------------------------- pair head: MFMA GEMM (K=32) + u_i + u_j
__global__ __launch_bounds__(256) void k_pair(const float* __restrict__ tpf, const float* __restrict__ Wp,
                                              const float* __restrict__ u, float* __restrict__ out){
  const int lane = threadIdx.x & 63, wave = threadIdx.x >> 6;
  const int rr = lane & 15, grp = lane >> 4;
  const int pairbase = blockIdx.x * 64 + wave * 16;
  const int i = (blockIdx.x * 64) >> 9;
  bf8 af;
  {
    const float* tr = tpf + (size_t)(pairbase + rr) * 32 + grp * 8;
#pragma unroll
    for (int j = 0; j < 8; ++j) af[j] = (short)f2b(tr[j]);
  }
  f4 acc[8];
#pragma unroll
  for (int t = 0; t < 8; ++t){
    bf8 bf;
    const float* wr = Wp + (size_t)(t * 16 + rr) * 32 + grp * 8;
#pragma unroll
    for (int j = 0; j < 8; ++j) bf[j] = (short)f2b(wr[j]);
    acc[t] = mfma16(af, bf, f4zero());
  }
  const float* ui = u + (size_t)i * 256;
#pragma unroll
  for (int t = 0; t < 8; ++t){
    int c = t * 16 + rr;
    float uic = ui[c];
#pragma unroll
    for (int r = 0; r < 4; ++r){
      int p = pairbase + grp * 4 + r;
      int j = p & 511;
      out[(size_t)p * 128 + c] = acc[t][r] + uic + u[(size_t)j * 256 + 128 + c];
    }
  }
}

// ================================================================ host
extern "C" void kernel_launch(void* const* d_in, const int* in_sizes, int n_in,
                              void* d_out, int out_size, void* d_ws, size_t ws_size,
                              hipStream_t stream){
  (void)in_sizes; (void)n_in; (void)out_size; (void)ws_size;
  const float* atom_feats = (const float*)d_in[0];
  const float* tpf        = (const float*)d_in[1];
  const float* W_cond     = (const float*)d_in[2];
  const float* W_ph       = (const float*)d_in[3];
  const float* W_pw       = (const float*)d_in[4];
  const float* W_mlp1     = (const float*)d_in[5];
  const float* W_mlp2     = (const float*)d_in[6];
  const float* pb_ln_w    = (const float*)d_in[7];
  const float* pb_ln_b    = (const float*)d_in[8];
  const float* pb_w       = (const float*)d_in[9];
  const float* sln_w      = (const float*)d_in[10];
  const float* qkv_w      = (const float*)d_in[11];
  const float* q_bias     = (const float*)d_in[12];
  const float* out_w      = (const float*)d_in[13];
  const float* out_b      = (const float*)d_in[14];
  const float* ada_w      = (const float*)d_in[15];
  const float* ta_w       = (const float*)d_in[16];
  const float* tb_w       = (const float*)d_in[17];
  const float* gate_w     = (const float*)d_in[18];
  const float* gate_b     = (const float*)d_in[19];
  const float* W_tok      = (const float*)d_in[20];
  const float* W_trunk    = (const float*)d_in[21];
  const float* W_struct   = (const float*)d_in[22];
  const float* W_pairin   = (const float*)d_in[23];
  const float* W_outer    = (const float*)d_in[24];
  const int*   a2t        = (const int*)d_in[28];

  char* wsb = (char*)d_ws;
  size_t off = 0;
  auto alc = [&](size_t bytes) -> void* {
    void* r = wsb + off;
    off = (off + bytes + 255) & ~(size_t)255;
    return r;
  };

  u16* sln_bfw   = (u16*)alc(98304 * 2);
  u16* qkv_bfw   = (u16*)alc(147456 * 2);
  u16* out_bfw   = (u16*)alc(49152 * 2);
  u16* ada_bfw   = (u16*)alc(98304 * 2);
  u16* ta_bfw    = (u16*)alc(196608 * 2);
  u16* tb_bfw    = (u16*)alc(98304 * 2);
  u16* gate_bfw  = (u16*)alc(49152 * 2);
  u16* tok_bfw   = (u16*)alc(49152 * 2);
  // trunk/struct/outer contiguous -> one concatenated [1024][384] weight for k_tok
  u16* trunk_bfw = (u16*)alc(147456 * 2);
  u16* struct_bfw= (u16*)alc(147456 * 2);
  u16* outer_bfw = (u16*)alc(98304 * 2);
  float* a_f     = (float*)alc((size_t)NATOMS * 128 * 4);
  float* lnA     = (float*)alc((size_t)NATOMS * 128 * 4);
  u16* sln_bf    = (u16*)alc((size_t)NATOMS * 128 * 2);
  u16* qkv_bf    = (u16*)alc((size_t)NATOMS * 384 * 2);
  float* ph      = (float*)alc((size_t)NATOMS * 16 * 4);
  float* pw      = (float*)alc((size_t)NATOMS * 16 * 4);
  float* bias    = (float*)alc((size_t)NBLK * 4 * 32 * 128 * 4);
  float* atom_out= bias; // alias: bias dead after layer-2 attention
  u16* tok_bf    = (u16*)alc(512 * 384 * 2);
  float* u_f     = (float*)alc(512 * 256 * 4);

  float* s_trunk  = (float*)d_out;
  float* s_struct = s_trunk + 512 * 384;
  float* pair_out = s_struct + 512 * 384;

  CvtArgs ca;
  const float* srcs[11] = {sln_w, qkv_w, out_w, ada_w, ta_w, tb_w, gate_w,
                           W_tok, W_trunk, W_struct, W_outer};
  u16* dsts[11] = {sln_bfw, qkv_bfw, out_bfw, ada_bfw, ta_bfw, tb_bfw, gate_bfw,
                   tok_bfw, trunk_bfw, struct_bfw, outer_bfw};
  int n4s[11] = {24576, 36864, 12288, 24576, 49152, 24576, 12288,
                 12288, 36864, 36864, 24576};
  for (int s = 0; s < 11; ++s){ ca.src[s] = srcs[s]; ca.dst[s] = dsts[s]; ca.n4[s] = n4s[s]; }
  k_convert<<<256, 256, 0, stream>>>(ca);

  k_cond_pre<<<736, 256, 0, stream>>>(atom_feats, W_cond, W_ph, W_pw, a_f, sln_bf, ph, pw,
                                      sln_bfw, qkv_bfw, q_bias, qkv_bf);
  k_pb<<<NBLK * 8, 256, 0, stream>>>(ph, pw, W_mlp1, W_mlp2, pb_ln_w, pb_ln_b, pb_w, bias);

  for (int l = 0; l < 3; ++l){
    const u16* outW  = out_bfw  + (size_t)l * 128 * 128;
    const u16* adaW  = ada_bfw  + (size_t)l * 256 * 128;
    const u16* taW   = ta_bfw   + (size_t)l * 512 * 128;
    const u16* tbW   = tb_bfw   + (size_t)l * 128 * 256;
    const u16* gateW = gate_bfw + (size_t)l * 128 * 128;
    k_attn<<<NBLK, 256, 0, stream>>>(qkv_bf, bias, outW, out_b + l * 128, a_f, lnA);
    if (l < 2){
      const u16* slnW2 = sln_bfw + (size_t)(l + 1) * 256 * 128;
      const u16* qkvW2 = qkv_bfw + (size_t)(l + 1) * 384 * 128;
      k_postpre<0><<<736, 256, 0, stream>>>(sln_bf, lnA, a_f, gateW, gate_b + l * 128,
                                            adaW, taW, tbW, slnW2, qkvW2,
                                            q_bias + (l + 1) * 128, qkv_bf,
                                            nullptr, nullptr);
    } else {
      k_postpre<1><<<736, 256, 0, stream>>>(sln_bf, lnA, a_f, gateW, gate_b + l * 128,
                                            adaW, taW, tbW, nullptr, nullptr,
                                            nullptr, nullptr,
                                            tok_bfw, atom_out);
    }
  }

  k_segmean<<<512, 256, 0, stream>>>(atom_out, a2t, tok_bf);
  k_tok<<<128, 256, 0, stream>>>(tok_bf, trunk_bfw, s_trunk, s_struct, u_f);
  k_pair<<<4096, 256, 0, stream>>>(tpf, W_pairin, u_f, pair_out);
}